// Round 4
// baseline (341.131 us; speedup 1.0000x reference)
//
#include <hip/hip_runtime.h>
#include <float.h>

#define BB 256
#define DD 256
#define KK 1024
#define EE 16
#define DECAY 0.999f
#define GAIN  0.001f
#define EPS   1e-6f

// output offsets in floats (tuple order: cw_embed, one_hot, new_codebook, new_ema)
#define OH_OFF   ((size_t)BB * DD * EE)                    // 1048576
#define CB_OFF   (OH_OFF + (size_t)BB * DD * KK)           // 68157440
#define EMA_OFF  (CB_OFF + (size_t)DD * KK * EE)           // 72351744

__device__ __forceinline__ float dot16(const float4& a0, const float4& a1,
                                       const float4& a2, const float4& a3,
                                       const float4& b0, const float4& b1,
                                       const float4& b2, const float4& b3) {
  float s = a0.x * b0.x;
  s = fmaf(a0.y, b0.y, s); s = fmaf(a0.z, b0.z, s); s = fmaf(a0.w, b0.w, s);
  s = fmaf(a1.x, b1.x, s); s = fmaf(a1.y, b1.y, s); s = fmaf(a1.z, b1.z, s); s = fmaf(a1.w, b1.w, s);
  s = fmaf(a2.x, b2.x, s); s = fmaf(a2.y, b2.y, s); s = fmaf(a2.z, b2.z, s); s = fmaf(a2.w, b2.w, s);
  s = fmaf(a3.x, b3.x, s); s = fmaf(a3.y, b3.y, s); s = fmaf(a3.z, b3.z, s); s = fmaf(a3.w, b3.w, s);
  return s;
}

// ---- K1: assignment + cw_embed + new_codebook + new_ema + idx (NO one_hot) ----
// One block per d, 512 threads = 8 waves; wave w scans k in [128w, 128w+128);
// each lane holds x for 4 b's -> 1 ds_read_b128 per dot16.
__global__ __launch_bounds__(512, 2) void vq_assign_update(
    const float* __restrict__ cw_q,      // (B, D*E)
    const float* __restrict__ codebook,  // (D, K, E)
    const float* __restrict__ ema,       // (D, K)
    float* __restrict__ out,
    int* __restrict__ idx_ws)            // (B, D) ints, row-major d-fastest
{
  __shared__ float4 cb4s[KK * EE / 4];   // 64 KB codebook row d
  __shared__ float4 upd4s[KK * EE / 4];  // 64 KB update accumulator
  __shared__ float  c2s[KK];             // 4 KB |c|^2, reused as esh
  __shared__ float  cnts[KK];            // 4 KB
  __shared__ float  pbest[8 * 256];      // 8 KB
  __shared__ int    pidxs[8 * 256];      // 8 KB
  __shared__ int    ish[BB];             // 1 KB

  const int t = threadIdx.x;
  const int d = blockIdx.x;
  const int w = t >> 6;
  const int l = t & 63;
  const float4 z4 = make_float4(0.f, 0.f, 0.f, 0.f);

  // ---- P0a: zero LDS accumulators ----
  #pragma unroll
  for (int j = 0; j < 2; ++j) cnts[t + 512 * j] = 0.f;
  #pragma unroll
  for (int i = 0; i < 8; ++i) upd4s[i * 512 + t] = z4;

  // ---- P0b: stage codebook row d -> LDS; c2 via 4-lane butterfly ----
  const float4* src4 = (const float4*)codebook + (size_t)d * (KK * EE / 4);
  #pragma unroll
  for (int i = 0; i < 8; ++i) {
    int i4 = i * 512 + t;
    float4 v = src4[i4];
    cb4s[i4] = v;
    float sq = v.x * v.x;
    sq = fmaf(v.y, v.y, sq);
    sq = fmaf(v.z, v.z, sq);
    sq = fmaf(v.w, v.w, sq);
    sq += __shfl_xor(sq, 1);
    sq += __shfl_xor(sq, 2);
    if ((t & 3) == 0) c2s[i4 >> 2] = sq;
  }

  // ---- x fragments for 4 b's per lane (b = l + 64j) ----
  float4 xv[4][4];
  float  x2[4];
  #pragma unroll
  for (int j = 0; j < 4; ++j) {
    const int b = l + 64 * j;
    const float4* xr = (const float4*)cw_q + (size_t)b * (DD * EE / 4) + d * 4;
    xv[j][0] = xr[0]; xv[j][1] = xr[1]; xv[j][2] = xr[2]; xv[j][3] = xr[3];
  }
  __syncthreads();

  #pragma unroll
  for (int j = 0; j < 4; ++j)
    x2[j] = dot16(xv[j][0], xv[j][1], xv[j][2], xv[j][3],
                  xv[j][0], xv[j][1], xv[j][2], xv[j][3]);

  float best[4] = {FLT_MAX, FLT_MAX, FLT_MAX, FLT_MAX};
  int   bi[4]   = {0, 0, 0, 0};
  const int kbase = w << 7;

  #pragma unroll 2
  for (int s = 0; s < 128; ++s) {
    const int k = kbase + s;
    const float4* p = cb4s + (k << 2);     // wave-uniform -> LDS broadcast
    float4 c0 = p[0], c1 = p[1], c2v = p[2], c3 = p[3];
    const float c2k = c2s[k];

    #pragma unroll
    for (int j = 0; j < 4; ++j) {
      float dj = dot16(c0, c1, c2v, c3, xv[j][0], xv[j][1], xv[j][2], xv[j][3]);
      float dist = fmaf(-2.f, dj, x2[j] + c2k);
      if (dist < best[j]) { best[j] = dist; bi[j] = k; }   // strict <: lowest k wins
    }
  }

  #pragma unroll
  for (int j = 0; j < 4; ++j) {
    pbest[w * 256 + l + 64 * j] = best[j];
    pidxs[w * 256 + l + 64 * j] = bi[j];
  }
  __syncthreads();

  // ---- P2: merge 8 k-ranges (ascending k, strict <), epilogue per b ----
  if (t < 256) {
    const int b = t;
    float bb = pbest[b];
    int   bidx = pidxs[b];
    #pragma unroll
    for (int w2 = 1; w2 < 8; ++w2) {
      float e = pbest[w2 * 256 + b];
      int   ii = pidxs[w2 * 256 + b];
      if (e < bb) { bb = e; bidx = ii; }
    }

    float4* ce = (float4*)out + (size_t)b * (DD * EE / 4) + d * 4;
    const float4* cwp = cb4s + (bidx << 2);
    ce[0] = cwp[0]; ce[1] = cwp[1]; ce[2] = cwp[2]; ce[3] = cwp[3];

    idx_ws[(size_t)b * DD + d] = bidx;     // for K2's scatter
    ish[b] = bidx;
    atomicAdd(&cnts[bidx], 1.0f);
  }
  __syncthreads();

  // ---- P3: update scatter, e-split so atomic addresses spread across banks ----
  {
    float* upd = (float*)upd4s;
    const int e = t & 15;
    const int g = t >> 4;                  // 32 groups handle 8 b's each
    #pragma unroll
    for (int i = 0; i < 8; ++i) {
      int b = g * 8 + i;
      int k = ish[b];
      float xvv = cw_q[(size_t)b * (DD * EE) + (size_t)d * EE + e];  // L1-hot
      atomicAdd(&upd[k * EE + e], xvv);
    }
  }
  __syncthreads();

  // ---- P4: new_ema + stage ema (reuse c2s) ----
  {
    const float* emad = ema + (size_t)d * KK;
    float* oe = out + EMA_OFF + (size_t)d * KK;
    #pragma unroll
    for (int j = 0; j < 2; ++j) {
      int k = t + 512 * j;
      float ev = emad[k];
      c2s[k] = ev;
      oe[k] = DECAY * ev + GAIN * cnts[k];
    }
  }
  __syncthreads();

  // ---- P5: new_codebook ----
  {
    float4* ocb = (float4*)(out + CB_OFF) + (size_t)d * (KK * EE / 4);
    #pragma unroll
    for (int i = 0; i < 8; ++i) {
      int i4 = i * 512 + t;
      int k  = i4 >> 2;
      float4 c = cb4s[i4];
      float4 u = upd4s[i4];
      float inv = GAIN / (c2s[k] + EPS);
      float4 r;
      r.x = DECAY * c.x + u.x * inv;
      r.y = DECAY * c.y + u.y * inv;
      r.z = DECAY * c.z + u.z * inv;
      r.w = DECAY * c.w + u.w * inv;
      ocb[i4] = r;
    }
  }
}

// ---- K2: one_hot = zeros + scatter 1.0, as a LINEAR grid-stride sweep ----
// Identical access shape to the rocclr fill kernel (proven 6.1 TB/s here).
// q indexes float4s of the one_hot region; row r = q>>8 = b*DD+d; the idx
// load is wave-uniform (64 consecutive q share r) -> broadcast, L1-hot.
__global__ __launch_bounds__(256) void vq_onehot_fill(
    const int* __restrict__ idx_ws,      // (B, D)
    float* __restrict__ out)
{
  const size_t total4 = (size_t)BB * DD * KK / 4;   // 16,777,216 float4
  float4* oh4 = (float4*)(out + OH_OFF);
  const size_t stride = (size_t)gridDim.x * blockDim.x;
  for (size_t q = (size_t)blockIdx.x * blockDim.x + threadIdx.x;
       q < total4; q += stride) {
    const int r = (int)(q >> 8);          // row (b*DD + d)
    const int c = ((int)q & 255) << 2;    // first k of this float4
    const int idx = idx_ws[r];
    float4 v;
    v.x = (idx == c)     ? 1.0f : 0.0f;
    v.y = (idx == c + 1) ? 1.0f : 0.0f;
    v.z = (idx == c + 2) ? 1.0f : 0.0f;
    v.w = (idx == c + 3) ? 1.0f : 0.0f;
    oh4[q] = v;
  }
}

extern "C" void kernel_launch(void* const* d_in, const int* in_sizes, int n_in,
                              void* d_out, int out_size, void* d_ws, size_t ws_size,
                              hipStream_t stream) {
  const float* cw_q     = (const float*)d_in[0];
  const float* codebook = (const float*)d_in[1];
  const float* ema      = (const float*)d_in[2];
  float* out  = (float*)d_out;
  int* idx_ws = (int*)d_ws;   // 256 KB
  (void)in_sizes; (void)n_in; (void)out_size; (void)ws_size;

  vq_assign_update<<<dim3(DD), dim3(512), 0, stream>>>(cw_q, codebook, ema, out, idx_ws);
  vq_onehot_fill<<<dim3(4096), dim3(256), 0, stream>>>(idx_ws, out);
}

// Round 6
// 334.392 us; speedup vs baseline: 1.0202x; 1.0202x over previous
//
#include <hip/hip_runtime.h>
#include <float.h>

#define BB 256
#define DD 256
#define KK 1024
#define EE 16
#define DECAY 0.999f
#define GAIN  0.001f
#define EPS   1e-6f

// output offsets in floats (tuple order: cw_embed, one_hot, new_codebook, new_ema)
#define OH_OFF   ((size_t)BB * DD * EE)                    // 1048576
#define CB_OFF   (OH_OFF + (size_t)BB * DD * KK)           // 68157440
#define EMA_OFF  (CB_OFF + (size_t)DD * KK * EE)           // 72351744

// native clang vector type: __builtin_nontemporal_store accepts this, not HIP float4
typedef float native_f4 __attribute__((ext_vector_type(4)));

__device__ __forceinline__ void nt_store4(const float4& v, float4* p) {
  native_f4 nv; nv.x = v.x; nv.y = v.y; nv.z = v.z; nv.w = v.w;
  __builtin_nontemporal_store(nv, reinterpret_cast<native_f4*>(p));
}

__device__ __forceinline__ float dot16(const float4& a0, const float4& a1,
                                       const float4& a2, const float4& a3,
                                       const float4& b0, const float4& b1,
                                       const float4& b2, const float4& b3) {
  float s = a0.x * b0.x;
  s = fmaf(a0.y, b0.y, s); s = fmaf(a0.z, b0.z, s); s = fmaf(a0.w, b0.w, s);
  s = fmaf(a1.x, b1.x, s); s = fmaf(a1.y, b1.y, s); s = fmaf(a1.z, b1.z, s); s = fmaf(a1.w, b1.w, s);
  s = fmaf(a2.x, b2.x, s); s = fmaf(a2.y, b2.y, s); s = fmaf(a2.z, b2.z, s); s = fmaf(a2.w, b2.w, s);
  s = fmaf(a3.x, b3.x, s); s = fmaf(a3.y, b3.y, s); s = fmaf(a3.z, b3.z, s); s = fmaf(a3.w, b3.w, s);
  return s;
}

// One block per d. 512 threads = 8 waves. Wave w scans k in [128w, 128w+128);
// each lane holds x for 4 b's (b = lane + 64j) -> 1 ds_read_b128 per dot.
// one_hot zero-fill interleaved with the scan (1 KB/wave-instr, nontemporal).
// LDS ~153 KB -> 1 block/CU, 8 waves/CU.
__global__ __launch_bounds__(512, 2) void vqvae_fused(
    const float* __restrict__ cw_q,      // (B, D*E)
    const float* __restrict__ codebook,  // (D, K, E)
    const float* __restrict__ ema,       // (D, K)
    float* __restrict__ out)
{
  __shared__ float4 cb4s[KK * EE / 4];   // 64 KB codebook row d
  __shared__ float4 upd4s[KK * EE / 4];  // 64 KB update accumulator
  __shared__ float  c2s[KK];             // 4 KB |c|^2, reused as esh
  __shared__ float  cnts[KK];            // 4 KB
  __shared__ float  pbest[8 * 256];      // 8 KB
  __shared__ int    pidxs[8 * 256];      // 8 KB
  __shared__ int    ish[BB];             // 1 KB

  const int t = threadIdx.x;
  const int d = blockIdx.x;
  const int w = t >> 6;
  const int l = t & 63;
  const float4 z4 = make_float4(0.f, 0.f, 0.f, 0.f);

  // ---- P0a: zero LDS accumulators ----
  #pragma unroll
  for (int j = 0; j < 2; ++j) cnts[t + 512 * j] = 0.f;
  #pragma unroll
  for (int i = 0; i < 8; ++i) upd4s[i * 512 + t] = z4;

  // ---- P0b: stage codebook row d -> LDS; c2 via 4-lane butterfly ----
  const float4* src4 = (const float4*)codebook + (size_t)d * (KK * EE / 4);
  #pragma unroll
  for (int i = 0; i < 8; ++i) {
    int i4 = i * 512 + t;
    float4 v = src4[i4];
    cb4s[i4] = v;
    float sq = v.x * v.x;
    sq = fmaf(v.y, v.y, sq);
    sq = fmaf(v.z, v.z, sq);
    sq = fmaf(v.w, v.w, sq);
    sq += __shfl_xor(sq, 1);
    sq += __shfl_xor(sq, 2);
    if ((t & 3) == 0) c2s[i4 >> 2] = sq;
  }

  // ---- x fragments for 4 b's per lane (b = l + 64j) ----
  float4 xv[4][4];
  float  x2[4];
  #pragma unroll
  for (int j = 0; j < 4; ++j) {
    const int b = l + 64 * j;
    const float4* xr = (const float4*)cw_q + (size_t)b * (DD * EE / 4) + d * 4;
    xv[j][0] = xr[0]; xv[j][1] = xr[1]; xv[j][2] = xr[2]; xv[j][3] = xr[3];
  }
  __syncthreads();

  #pragma unroll
  for (int j = 0; j < 4; ++j)
    x2[j] = dot16(xv[j][0], xv[j][1], xv[j][2], xv[j][3],
                  xv[j][0], xv[j][1], xv[j][2], xv[j][3]);

  float best[4] = {FLT_MAX, FLT_MAX, FLT_MAX, FLT_MAX};
  int   bi[4]   = {0, 0, 0, 0};
  const int kbase = w << 7;

  float* ohp = out + OH_OFF;
  // wave w zero-fills one_hot rows [32w, 32w+32) for column block d (all 1024 k)
  float4* zb = (float4*)(ohp + (size_t)(w << 5) * (DD * KK) + (size_t)d * KK) + l;

  #pragma unroll 2
  for (int s = 0; s < 128; ++s) {
    const int k = kbase + s;
    const float4* p = cb4s + (k << 2);     // wave-uniform -> LDS broadcast
    float4 c0 = p[0], c1 = p[1], c2v = p[2], c3 = p[3];
    const float c2k = c2s[k];

    #pragma unroll
    for (int j = 0; j < 4; ++j) {
      float dj = dot16(c0, c1, c2v, c3, xv[j][0], xv[j][1], xv[j][2], xv[j][3]);
      float dist = fmaf(-2.f, dj, x2[j] + c2k);
      if (dist < best[j]) { best[j] = dist; bi[j] = k; }   // strict <: lowest k wins
    }

    // interleaved zero-fill: iter s -> local row s>>2, k-quarter s&3 (1 KB/wave, NT)
    nt_store4(z4, zb + (size_t)(s >> 2) * (DD * KK / 4) + (s & 3) * 64);
  }

  #pragma unroll
  for (int j = 0; j < 4; ++j) {
    pbest[w * 256 + l + 64 * j] = best[j];
    pidxs[w * 256 + l + 64 * j] = bi[j];
  }
  __syncthreads();   // drains zero-stores (vmcnt) + LDS partials

  // ---- P2: merge 8 k-ranges (ascending k, strict <), epilogue per b ----
  if (t < 256) {
    const int b = t;
    float bb = pbest[b];
    int   bidx = pidxs[b];
    #pragma unroll
    for (int w2 = 1; w2 < 8; ++w2) {
      float e = pbest[w2 * 256 + b];
      int   ii = pidxs[w2 * 256 + b];
      if (e < bb) { bb = e; bidx = ii; }
    }

    float4* ce = (float4*)out + (size_t)b * (DD * EE / 4) + d * 4;
    const float4* cwp = cb4s + (bidx << 2);
    nt_store4(cwp[0], ce + 0);
    nt_store4(cwp[1], ce + 1);
    nt_store4(cwp[2], ce + 2);
    nt_store4(cwp[3], ce + 3);

    // normal store: must land after this block's NT zeros (barrier drained vmcnt)
    ohp[(size_t)b * (DD * KK) + (size_t)d * KK + bidx] = 1.0f;

    ish[b] = bidx;
    atomicAdd(&cnts[bidx], 1.0f);
  }
  __syncthreads();

  // ---- P3: update scatter, e-split so atomic addresses spread across banks ----
  {
    float* upd = (float*)upd4s;
    const int e = t & 15;
    const int g = t >> 4;                  // 32 groups handle 8 b's each
    #pragma unroll
    for (int i = 0; i < 8; ++i) {
      int b = g * 8 + i;
      int k = ish[b];
      float xvv = cw_q[(size_t)b * (DD * EE) + (size_t)d * EE + e];  // L1-hot
      atomicAdd(&upd[k * EE + e], xvv);
    }
  }
  __syncthreads();

  // ---- P4: new_ema + stage ema (reuse c2s) ----
  {
    const float* emad = ema + (size_t)d * KK;
    float* oe = out + EMA_OFF + (size_t)d * KK;
    #pragma unroll
    for (int j = 0; j < 2; ++j) {
      int k = t + 512 * j;
      float ev = emad[k];
      c2s[k] = ev;
      __builtin_nontemporal_store(DECAY * ev + GAIN * cnts[k], oe + k);
    }
  }
  __syncthreads();

  // ---- P5: new_codebook ----
  {
    float4* ocb = (float4*)(out + CB_OFF) + (size_t)d * (KK * EE / 4);
    #pragma unroll
    for (int i = 0; i < 8; ++i) {
      int i4 = i * 512 + t;
      int k  = i4 >> 2;
      float4 c = cb4s[i4];
      float4 u = upd4s[i4];
      float inv = GAIN / (c2s[k] + EPS);
      float4 r;
      r.x = DECAY * c.x + u.x * inv;
      r.y = DECAY * c.y + u.y * inv;
      r.z = DECAY * c.z + u.z * inv;
      r.w = DECAY * c.w + u.w * inv;
      nt_store4(r, ocb + i4);
    }
  }
}

extern "C" void kernel_launch(void* const* d_in, const int* in_sizes, int n_in,
                              void* d_out, int out_size, void* d_ws, size_t ws_size,
                              hipStream_t stream) {
  const float* cw_q     = (const float*)d_in[0];
  const float* codebook = (const float*)d_in[1];
  const float* ema      = (const float*)d_in[2];
  float* out = (float*)d_out;
  (void)in_sizes; (void)n_in; (void)out_size; (void)d_ws; (void)ws_size;

  vqvae_fused<<<dim3(DD), dim3(512), 0, stream>>>(cw_q, codebook, ema, out);
}

// Round 7
// 333.741 us; speedup vs baseline: 1.0221x; 1.0019x over previous
//
#include <hip/hip_runtime.h>
#include <float.h>

#define BB 256
#define DD 256
#define KK 1024
#define EE 16
#define DECAY 0.999f
#define GAIN  0.001f
#define EPS   1e-6f

// output offsets in floats (tuple order: cw_embed, one_hot, new_codebook, new_ema)
#define OH_OFF   ((size_t)BB * DD * EE)                    // 1048576
#define CB_OFF   (OH_OFF + (size_t)BB * DD * KK)           // 68157440
#define EMA_OFF  (CB_OFF + (size_t)DD * KK * EE)           // 72351744

__device__ __forceinline__ float dot16(const float4& a0, const float4& a1,
                                       const float4& a2, const float4& a3,
                                       const float4& b0, const float4& b1,
                                       const float4& b2, const float4& b3) {
  float s = a0.x * b0.x;
  s = fmaf(a0.y, b0.y, s); s = fmaf(a0.z, b0.z, s); s = fmaf(a0.w, b0.w, s);
  s = fmaf(a1.x, b1.x, s); s = fmaf(a1.y, b1.y, s); s = fmaf(a1.z, b1.z, s); s = fmaf(a1.w, b1.w, s);
  s = fmaf(a2.x, b2.x, s); s = fmaf(a2.y, b2.y, s); s = fmaf(a2.z, b2.z, s); s = fmaf(a2.w, b2.w, s);
  s = fmaf(a3.x, b3.x, s); s = fmaf(a3.y, b3.y, s); s = fmaf(a3.z, b3.z, s); s = fmaf(a3.w, b3.w, s);
  return s;
}

// One block per d. 512 threads = 8 waves. Wave w scans k in [128w, 128w+128);
// each lane holds x for 4 b's (b = lane + 64j) -> 1 ds_read_b128 per dot.
// one_hot zero-fill interleaved as full float4 (1 KB/wave-instr) stores.
// LDS ~153 KB -> 1 block/CU, 8 waves/CU.
// NOTE: nontemporal stores measurably REGRESS this kernel (R6: +16 us) —
// the scattered 1.0 dword store needs the zero-filled line still in L2.
__global__ __launch_bounds__(512, 2) void vqvae_fused(
    const float* __restrict__ cw_q,      // (B, D*E)
    const float* __restrict__ codebook,  // (D, K, E)
    const float* __restrict__ ema,       // (D, K)
    float* __restrict__ out)
{
  __shared__ float4 cb4s[KK * EE / 4];   // 64 KB codebook row d
  __shared__ float4 upd4s[KK * EE / 4];  // 64 KB update accumulator
  __shared__ float  c2s[KK];             // 4 KB |c|^2, reused as esh
  __shared__ float  cnts[KK];            // 4 KB
  __shared__ float  pbest[8 * 256];      // 8 KB
  __shared__ int    pidxs[8 * 256];      // 8 KB
  __shared__ int    ish[BB];             // 1 KB

  const int t = threadIdx.x;
  const int d = blockIdx.x;
  const int w = t >> 6;
  const int l = t & 63;
  const float4 z4 = make_float4(0.f, 0.f, 0.f, 0.f);

  // ---- P0a: zero LDS accumulators ----
  #pragma unroll
  for (int j = 0; j < 2; ++j) cnts[t + 512 * j] = 0.f;
  #pragma unroll
  for (int i = 0; i < 8; ++i) upd4s[i * 512 + t] = z4;

  // ---- P0b: stage codebook row d -> LDS; c2 via 4-lane butterfly ----
  const float4* src4 = (const float4*)codebook + (size_t)d * (KK * EE / 4);
  #pragma unroll
  for (int i = 0; i < 8; ++i) {
    int i4 = i * 512 + t;
    float4 v = src4[i4];
    cb4s[i4] = v;
    float sq = v.x * v.x;
    sq = fmaf(v.y, v.y, sq);
    sq = fmaf(v.z, v.z, sq);
    sq = fmaf(v.w, v.w, sq);
    sq += __shfl_xor(sq, 1);
    sq += __shfl_xor(sq, 2);
    if ((t & 3) == 0) c2s[i4 >> 2] = sq;
  }

  // ---- x fragments for 4 b's per lane (b = l + 64j) ----
  float4 xv[4][4];
  float  x2[4];
  #pragma unroll
  for (int j = 0; j < 4; ++j) {
    const int b = l + 64 * j;
    const float4* xr = (const float4*)cw_q + (size_t)b * (DD * EE / 4) + d * 4;
    xv[j][0] = xr[0]; xv[j][1] = xr[1]; xv[j][2] = xr[2]; xv[j][3] = xr[3];
  }
  __syncthreads();

  #pragma unroll
  for (int j = 0; j < 4; ++j)
    x2[j] = dot16(xv[j][0], xv[j][1], xv[j][2], xv[j][3],
                  xv[j][0], xv[j][1], xv[j][2], xv[j][3]);

  float best[4] = {FLT_MAX, FLT_MAX, FLT_MAX, FLT_MAX};
  int   bi[4]   = {0, 0, 0, 0};
  const int kbase = w << 7;

  float* ohp = out + OH_OFF;
  // wave w zero-fills one_hot rows [32w, 32w+32) for column block d (all 1024 k)
  float4* zb = (float4*)(ohp + (size_t)(w << 5) * (DD * KK) + (size_t)d * KK) + l;

  #pragma unroll 2
  for (int s = 0; s < 128; ++s) {
    const int k = kbase + s;
    const float4* p = cb4s + (k << 2);     // wave-uniform -> LDS broadcast
    float4 c0 = p[0], c1 = p[1], c2v = p[2], c3 = p[3];
    const float c2k = c2s[k];

    #pragma unroll
    for (int j = 0; j < 4; ++j) {
      float dj = dot16(c0, c1, c2v, c3, xv[j][0], xv[j][1], xv[j][2], xv[j][3]);
      float dist = fmaf(-2.f, dj, x2[j] + c2k);
      if (dist < best[j]) { best[j] = dist; bi[j] = k; }   // strict <: lowest k wins
    }

    // interleaved zero-fill: iter s -> local row s>>2, k-quarter s&3 (1 KB/wave)
    zb[(size_t)(s >> 2) * (DD * KK / 4) + (s & 3) * 64] = z4;
  }

  #pragma unroll
  for (int j = 0; j < 4; ++j) {
    pbest[w * 256 + l + 64 * j] = best[j];
    pidxs[w * 256 + l + 64 * j] = bi[j];
  }
  __syncthreads();   // drains zero-stores (vmcnt) + LDS partials

  // ---- P2: merge 8 k-ranges (ascending k, strict <), epilogue per b ----
  if (t < 256) {
    const int b = t;
    float bb = pbest[b];
    int   bidx = pidxs[b];
    #pragma unroll
    for (int w2 = 1; w2 < 8; ++w2) {
      float e = pbest[w2 * 256 + b];
      int   ii = pidxs[w2 * 256 + b];
      if (e < bb) { bb = e; bidx = ii; }
    }

    float4* ce = (float4*)out + (size_t)b * (DD * EE / 4) + d * 4;
    const float4* cwp = cb4s + (bidx << 2);
    ce[0] = cwp[0]; ce[1] = cwp[1]; ce[2] = cwp[2]; ce[3] = cwp[3];

    ohp[(size_t)b * (DD * KK) + (size_t)d * KK + bidx] = 1.0f;

    ish[b] = bidx;
    atomicAdd(&cnts[bidx], 1.0f);
  }
  __syncthreads();

  // ---- P3: update scatter, e-split so atomic addresses spread across banks ----
  {
    float* upd = (float*)upd4s;
    const int e = t & 15;
    const int g = t >> 4;                  // 32 groups handle 8 b's each
    #pragma unroll
    for (int i = 0; i < 8; ++i) {
      int b = g * 8 + i;
      int k = ish[b];
      float xvv = cw_q[(size_t)b * (DD * EE) + (size_t)d * EE + e];  // L1-hot
      atomicAdd(&upd[k * EE + e], xvv);
    }
  }
  __syncthreads();

  // ---- P4: new_ema + stage ema (reuse c2s) ----
  {
    const float* emad = ema + (size_t)d * KK;
    float* oe = out + EMA_OFF + (size_t)d * KK;
    #pragma unroll
    for (int j = 0; j < 2; ++j) {
      int k = t + 512 * j;
      float ev = emad[k];
      c2s[k] = ev;
      oe[k] = DECAY * ev + GAIN * cnts[k];
    }
  }
  __syncthreads();

  // ---- P5: new_codebook ----
  {
    float4* ocb = (float4*)(out + CB_OFF) + (size_t)d * (KK * EE / 4);
    #pragma unroll
    for (int i = 0; i < 8; ++i) {
      int i4 = i * 512 + t;
      int k  = i4 >> 2;
      float4 c = cb4s[i4];
      float4 u = upd4s[i4];
      float inv = GAIN / (c2s[k] + EPS);
      float4 r;
      r.x = DECAY * c.x + u.x * inv;
      r.y = DECAY * c.y + u.y * inv;
      r.z = DECAY * c.z + u.z * inv;
      r.w = DECAY * c.w + u.w * inv;
      ocb[i4] = r;
    }
  }
}

extern "C" void kernel_launch(void* const* d_in, const int* in_sizes, int n_in,
                              void* d_out, int out_size, void* d_ws, size_t ws_size,
                              hipStream_t stream) {
  const float* cw_q     = (const float*)d_in[0];
  const float* codebook = (const float*)d_in[1];
  const float* ema      = (const float*)d_in[2];
  float* out = (float*)d_out;
  (void)in_sizes; (void)n_in; (void)out_size; (void)d_ws; (void)ws_size;

  vqvae_fused<<<dim3(DD), dim3(512), 0, stream>>>(cw_q, codebook, ema, out);
}